// Round 1
// baseline (39.639 us; speedup 1.0000x reference)
//
#include <hip/hip_runtime.h>

// CORN loss: logits [B, K-1] fp32, targets [B] int (1..K), out = mean loss (fp32 scalar)
// B = 4194304, K = 10 -> 9 logits/row, 37.7M loss terms.
// loss(x, bt) = -log(sigmoid(bt ? x : -x) + 1e-7)   [since 1-sigmoid(x) = sigmoid(-x)]

#define BATCH    4194304
#define KM1      9
#define EPS_F    1e-7f

constexpr int BLOCKS  = 2048;
constexpr int THREADS = 256;

__global__ __launch_bounds__(THREADS) void corn_partial_kernel(
    const float* __restrict__ logits,
    const int*   __restrict__ targets,
    float*       __restrict__ partials) {
    const int tid      = blockIdx.x * THREADS + threadIdx.x;
    const int nthreads = BLOCKS * THREADS;
    const int ngroups  = BATCH / 4;  // 1048576 groups of 4 rows; exactly 2 per thread

    float acc = 0.0f;
    for (int g = tid; g < ngroups; g += nthreads) {
        const int row0 = g * 4;
        // 4 targets, 16B-aligned (row0 % 4 == 0)
        const int4 t4 = *reinterpret_cast<const int4*>(targets + row0);
        const int rank[4] = { t4.x - 1, t4.y - 1, t4.z - 1, t4.w - 1 };

        // 4 rows * 9 logits = 36 floats = 9 float4; byte offset 576*g -> 16B aligned
        const float4* src = reinterpret_cast<const float4*>(logits + (size_t)row0 * KM1);
        float4 v[9];
        #pragma unroll
        for (int i = 0; i < 9; ++i) v[i] = src[i];
        const float* f = reinterpret_cast<const float*>(v);  // all indexing below is compile-time

        #pragma unroll
        for (int r = 0; r < 4; ++r) {
            const int rk = rank[r];
            #pragma unroll
            for (int k = 0; k < 9; ++k) {
                const float x = f[r * 9 + k];
                const float y = (k < rk) ? x : -x;       // bt=1 -> +x, bt=0 -> -x
                const float p = 1.0f / (1.0f + __expf(-y));
                acc -= __logf(p + EPS_F);
            }
        }
    }

    // wave (64-lane) butterfly reduce
    #pragma unroll
    for (int off = 32; off > 0; off >>= 1)
        acc += __shfl_down(acc, off, 64);

    __shared__ float smem[THREADS / 64];
    if ((threadIdx.x & 63) == 0) smem[threadIdx.x >> 6] = acc;
    __syncthreads();
    if (threadIdx.x == 0) {
        float s = smem[0] + smem[1] + smem[2] + smem[3];
        partials[blockIdx.x] = s;   // deterministic: fixed tree, no atomics
    }
}

__global__ __launch_bounds__(256) void corn_final_kernel(
    const float* __restrict__ partials,
    float*       __restrict__ out) {
    float acc = 0.0f;
    for (int i = threadIdx.x; i < BLOCKS; i += 256)
        acc += partials[i];

    #pragma unroll
    for (int off = 32; off > 0; off >>= 1)
        acc += __shfl_down(acc, off, 64);

    __shared__ float smem[4];
    if ((threadIdx.x & 63) == 0) smem[threadIdx.x >> 6] = acc;
    __syncthreads();
    if (threadIdx.x == 0) {
        const float inv_n = 1.0f / (float)(BATCH * KM1);  // 37748736, exactly representable
        out[0] = (smem[0] + smem[1] + smem[2] + smem[3]) * inv_n;
    }
}

extern "C" void kernel_launch(void* const* d_in, const int* in_sizes, int n_in,
                              void* d_out, int out_size, void* d_ws, size_t ws_size,
                              hipStream_t stream) {
    const float* logits  = (const float*)d_in[0];
    const int*   targets = (const int*)d_in[1];
    float*       out     = (float*)d_out;
    float*       partials = (float*)d_ws;  // 2048 floats = 8 KB scratch

    corn_partial_kernel<<<BLOCKS, THREADS, 0, stream>>>(logits, targets, partials);
    corn_final_kernel<<<1, 256, 0, stream>>>(partials, out);
}